// Round 8
// baseline (153.049 us; speedup 1.0000x reference)
//
#include <hip/hip_runtime.h>
#include <hip/hip_bf16.h>
#include <stdint.h>

typedef short short8 __attribute__((ext_vector_type(8)));
typedef float f32x4 __attribute__((ext_vector_type(4)));

#define MDIM 8192
#define KDIM 1024
#define NDIM 1024
#define NKT  16

// ---------- helpers ----------

__device__ __forceinline__ unsigned short f2bf(float f) {
  union { float f; unsigned int u; } v; v.f = f;
  unsigned int u = v.u;
  u += 0x7fffu + ((u >> 16) & 1u);
  return (unsigned short)(u >> 16);
}

__device__ __forceinline__ void load_lds16(const void* gsrc, void* ldst) {
  __builtin_amdgcn_global_load_lds(
      (__attribute__((address_space(1))) void*)gsrc,
      (__attribute__((address_space(3))) void*)ldst,
      16, 0, 0);
}

__device__ __forceinline__ float fast_sigmoid(float x) {
  return 1.0f / (1.0f + __expf(-x));
}

__device__ __forceinline__ float fast_tanh(float x) {
  x = fminf(30.0f, fmaxf(-30.0f, x));
  float e = __expf(-2.0f * x);
  return (1.0f - e) / (1.0f + e);
}

// ---------- conversion kernels (tiled bf16 workspace) ----------

// hprev f32 [M][K] -> A_t[kt][M][64] bf16 (K-tile panels, 128 B rows)
__global__ void convert_h_tiled(const float* __restrict__ in,
                                unsigned short* __restrict__ out, int nchunk) {
  int idx = blockIdx.x * blockDim.x + threadIdx.x;
  int stride = gridDim.x * blockDim.x;
  for (int i = idx; i < nchunk; i += stride) {
    int r = i >> 7;
    int kc8 = i & 127;
    const float4* src = reinterpret_cast<const float4*>(in + (size_t)r * KDIM + kc8 * 8);
    float4 v0 = src[0], v1 = src[1];
    short8 o;
    o[0] = (short)f2bf(v0.x); o[1] = (short)f2bf(v0.y);
    o[2] = (short)f2bf(v0.z); o[3] = (short)f2bf(v0.w);
    o[4] = (short)f2bf(v1.x); o[5] = (short)f2bf(v1.y);
    o[6] = (short)f2bf(v1.z); o[7] = (short)f2bf(v1.w);
    int kt = kc8 >> 3;
    int c8 = kc8 & 7;
    reinterpret_cast<short8*>(out)[((size_t)kt * MDIM + r) * 8 + c8] = o;
  }
}

// w[k][n] f32 -> B_t[kt][g][N][64] bf16 (transpose + tile, 128 B rows)
__global__ void convert_w_tiled(const float* __restrict__ w0,
                                const float* __restrict__ w1,
                                const float* __restrict__ w2,
                                const float* __restrict__ w3,
                                unsigned short* __restrict__ out) {
  __shared__ float tile[64][65];
  int g = blockIdx.z;
  const float* w = (g == 0) ? w0 : (g == 1) ? w1 : (g == 2) ? w2 : w3;
  int kt = blockIdx.y;
  int k0 = kt * 64;
  int n0 = blockIdx.x * 64;
  int tx = threadIdx.x;
  int ty = threadIdx.y;
#pragma unroll
  for (int j = 0; j < 16; ++j) {
    int kk = ty * 16 + j;
    tile[kk][tx] = w[(size_t)(k0 + kk) * NDIM + n0 + tx];
  }
  __syncthreads();
#pragma unroll
  for (int j = 0; j < 16; ++j) {
    int nn = ty * 16 + j;
    out[(((size_t)kt * 4 + g) * NDIM + n0 + nn) * 64 + tx] = f2bf(tile[tx][nn]);
  }
}

// ---------- fused 4-gate GEMM: pair-tile persistent 8-phase pipeline ----
//
// 256 blocks (1/CU), 512 thr = 8 waves (2M x 4N). Each block computes TWO
// output tiles (brow, brow+256) x (4 gates x 64 cols) back-to-back as one
// 32-virtual-K-tile loop -- the pipeline (3 half-tiles, vmcnt(6)) never
// drains across the boundary, amortizing the short-K ramp; B (same nb for
// both) is fetched once. Mid-loop epilogue for tile 0 after vt=15.
// LDS/schedule identical to R7 (validated): 2 x 64 KB buf, XOR chunk
// swizzle (0 conflicts), 4 phases per K-tile, vmcnt(6) once per tile.

#define X0 0
#define X1 65536

#define BAR() __builtin_amdgcn_s_barrier()
#define LGKM0() do { \
    asm volatile("s_waitcnt lgkmcnt(0)" ::: "memory"); \
    __builtin_amdgcn_sched_barrier(0); } while (0)
#define VM6() asm volatile("s_waitcnt vmcnt(6)" ::: "memory")

// vt = virtual tile 0..31 (wraps mod 32): kt = vt&15, A-panel select vt>>4.
#define STG_A(BUF, vt, h) do { \
    const uint32_t _vv = (uint32_t)(vt) & 31u; \
    const uint32_t _oA = ((_vv & 15u) << 20) + ((_vv >> 4) << 15) + srcA + (h) * 16384; \
    load_lds16(ab + _oA,        ldsb + (BUF) + (h) * 16384 + tid * 16); \
    load_lds16(ab + _oA + 8192, ldsb + (BUF) + (h) * 16384 + 8192 + tid * 16); } while (0)
#define STG_B(BUF, vt, h) do { \
    const uint32_t _vv = (uint32_t)(vt) & 15u; \
    const uint32_t _oB = (_vv << 19) + srcB0 + (h) * 262144; \
    load_lds16(bb + _oB,          ldsb + (BUF) + 32768 + (h) * 16384 + tid * 16); \
    load_lds16(bb + _oB + 131072, ldsb + (BUF) + 32768 + (h) * 16384 + 8192 + tid * 16); } while (0)

#define LDB_ALL(CB) do { \
    _Pragma("unroll") for (int g = 0; g < 4; ++g) { \
      Br[g * 2 + 0] = *(const short8*)(ldsb + (CB) + b_base + g * 8192 + s0v); \
      Br[g * 2 + 1] = *(const short8*)(ldsb + (CB) + b_base + g * 8192 + s1v); } } while (0)
#define LDA_Q(CB, qm) do { \
    _Pragma("unroll") for (int f = 0; f < 4; ++f) { \
      Ar[f * 2 + 0] = *(const short8*)(ldsb + (CB) + a_base + ((qm) * 64 + f * 16) * 128 + s0v); \
      Ar[f * 2 + 1] = *(const short8*)(ldsb + (CB) + a_base + ((qm) * 64 + f * 16) * 128 + s1v); } } while (0)

#define MFMAQ(qm, qn) do { \
    __builtin_amdgcn_s_setprio(1); \
    _Pragma("unroll") for (int kk = 0; kk < 2; ++kk) \
    _Pragma("unroll") for (int f = 0; f < 4; ++f) \
    _Pragma("unroll") for (int gg = 0; gg < 2; ++gg) \
      acc[(qn) * 2 + gg][(qm) * 4 + f] = __builtin_amdgcn_mfma_f32_16x16x32_bf16( \
          Ar[f * 2 + kk], Br[((qn) * 2 + gg) * 2 + kk], \
          acc[(qn) * 2 + gg][(qm) * 4 + f], 0, 0, 0); \
    __builtin_amdgcn_s_setprio(0); } while (0)

// One K-tile block: compute from CB; stage (tA1).A1->OB, (tN2).{B0,B1,A0}->CB.
#define BLOCK4(CB, OB, tA1, tN2) do { \
    LDB_ALL(CB); LDA_Q(CB, 0); \
    STG_A(OB, tA1, 1); \
    BAR(); LGKM0(); MFMAQ(0, 0); BAR(); \
    STG_B(CB, tN2, 0); \
    BAR(); MFMAQ(0, 1); BAR(); \
    LDA_Q(CB, 1); \
    STG_B(CB, tN2, 1); \
    BAR(); LGKM0(); MFMAQ(1, 0); BAR(); \
    STG_A(CB, tN2, 0); \
    BAR(); MFMAQ(1, 1); VM6(); BAR(); } while (0)

#define EPILOG(brow_) do { \
    const int cc = bcol + wc * 16 + r15; \
    const float bi = b_i[cc], bff = b_f[cc], bg = b_g[cc], bo = b_o[cc]; \
    _Pragma("unroll") for (int m = 0; m < 8; ++m) { \
      _Pragma("unroll") for (int j = 0; j < 4; ++j) { \
        int rr = (brow_) + wr * 128 + m * 16 + hh * 4 + j; \
        size_t base = (size_t)rr * NDIM + cc; \
        float pi = acc[0][m][j] + bi; \
        float pf = acc[1][m][j] + bff; \
        float pg = acc[2][m][j] + bg; \
        float po = acc[3][m][j] + bo; \
        float iv = fast_sigmoid(pi); \
        float fv = fast_sigmoid(pf); \
        float gv = fast_tanh(pg); \
        float ov = fast_sigmoid(po); \
        float cp = fv * cprev[base] + iv * gv; \
        float hp = ov * fast_tanh(cp); \
        out[base] = hp; \
        out[outC + base] = cp; \
      } } } while (0)

__global__ __launch_bounds__(512, 2) void lstm_fused_gemm(
    const unsigned short* __restrict__ At,    // [16][8192][64] bf16
    const unsigned short* __restrict__ Bt,    // [16][4][1024][64] bf16
    const float* __restrict__ cprev,
    const float* __restrict__ b_i, const float* __restrict__ b_f,
    const float* __restrict__ b_g, const float* __restrict__ b_o,
    float* __restrict__ out)
{
  extern __shared__ unsigned char ldsb[];
  const int tid  = threadIdx.x;
  const int lane = tid & 63;
  const int wave = tid >> 6;
  const int wr = wave >> 2;   // 0..1 : rows wr*128..+128
  const int wc = wave & 3;    // 0..3 : cols wc*16..+16 per gate
  const int r15 = lane & 15;
  const int hh  = lane >> 4;

  // 256 blocks: XCD gets 32 = 2 nb x 16 mb-pairs.
  int bid = blockIdx.x;
  int loc = bid >> 3;                    // 0..31
  int nb = (bid & 7) * 2 + (loc >> 4);   // 0..15
  int mbp = loc & 15;                    // 0..15
  int brow0 = mbp * 512;
  int brow1 = brow0 + 256;
  int bcol = nb * 64;

  const char* ab = (const char*)At;
  const char* bb = (const char*)Bt;

  // staging source (pre-swizzled chunk within each 128 B line)
  const int srow = tid >> 3;
  const int cx = (((tid & 7) ^ (srow & 7)) << 4);
  const uint32_t srcA  = (uint32_t)(brow0 + srow) * 128 + cx;  // +32768 for brow1
  const uint32_t srcB0 = (uint32_t)(bcol + srow) * 128 + cx;

  // fragment read bases
  const uint32_t a_base = (uint32_t)(wr * 128 + r15) * 128;
  const uint32_t b_base = 32768u + (uint32_t)(wc * 16 + r15) * 128;
  const int s0v = ((hh ^ (r15 & 7)) << 4);
  const int s1v = s0v ^ 64;

  const size_t outC = (size_t)MDIM * NDIM;

  f32x4 acc[4][8];
#pragma unroll
  for (int g = 0; g < 4; ++g)
#pragma unroll
    for (int m = 0; m < 8; ++m)
      acc[g][m] = (f32x4){0.f, 0.f, 0.f, 0.f};

  short8 Ar[8], Br[8];

  // prologue: vt0 complete -> X0 (8 loads), vt1.{B0,B1,A0} -> X1 (6 loads)
  STG_A(X0, 0, 0); STG_A(X0, 0, 1);
  STG_B(X0, 0, 0); STG_B(X0, 0, 1);
  STG_B(X1, 1, 0); STG_B(X1, 1, 1);
  STG_A(X1, 1, 0);
  VM6();
  BAR();

  for (int vp = 0; vp < 16; ++vp) {
    const int v = 2 * vp;
    BLOCK4(X0, X1, v + 1, v + 2);
    BLOCK4(X1, X0, v + 2, v + 3);
    if (vp == 7) {
      EPILOG(brow0);
#pragma unroll
      for (int g = 0; g < 4; ++g)
#pragma unroll
        for (int m = 0; m < 8; ++m)
          acc[g][m] = (f32x4){0.f, 0.f, 0.f, 0.f};
    }
  }

  EPILOG(brow1);
}

// ---------- launch ----------

extern "C" void kernel_launch(void* const* d_in, const int* in_sizes, int n_in,
                              void* d_out, int out_size, void* d_ws, size_t ws_size,
                              hipStream_t stream) {
  const float* hprev = (const float*)d_in[0];
  const float* cprev = (const float*)d_in[1];
  const float* w_hi  = (const float*)d_in[2];
  const float* b_hi  = (const float*)d_in[3];
  const float* w_hf  = (const float*)d_in[4];
  const float* b_hf  = (const float*)d_in[5];
  const float* w_hg  = (const float*)d_in[6];
  const float* b_hg  = (const float*)d_in[7];
  const float* w_ho  = (const float*)d_in[8];
  const float* b_ho  = (const float*)d_in[9];
  float* out = (float*)d_out;

  // ws: [0,16MB) A_t; [16MB,24MB) B_t
  unsigned short* At = (unsigned short*)d_ws;
  unsigned short* Bt = (unsigned short*)((char*)d_ws + (size_t)NKT * MDIM * 64 * 2);

  convert_h_tiled<<<2048, 256, 0, stream>>>(hprev, At, MDIM * KDIM / 8);
  convert_w_tiled<<<dim3(16, 16, 4), dim3(64, 4, 1), 0, stream>>>(
      w_hi, w_hf, w_hg, w_ho, Bt);
  lstm_fused_gemm<<<256, 512, 131072, stream>>>(At, Bt, cprev,
                                                b_hi, b_hf, b_hg, b_ho, out);
}

// Round 9
// 114.986 us; speedup vs baseline: 1.3310x; 1.3310x over previous
//
#include <hip/hip_runtime.h>
#include <hip/hip_bf16.h>
#include <stdint.h>

typedef short short8 __attribute__((ext_vector_type(8)));
typedef float f32x16 __attribute__((ext_vector_type(16)));

#define MDIM 8192
#define KDIM 1024
#define NDIM 1024
#define NKT  16

// ---------- helpers ----------

__device__ __forceinline__ unsigned short f2bf(float f) {
  union { float f; unsigned int u; } v; v.f = f;
  unsigned int u = v.u;
  u += 0x7fffu + ((u >> 16) & 1u);
  return (unsigned short)(u >> 16);
}

__device__ __forceinline__ void load_lds16(const void* gsrc, void* ldst) {
  __builtin_amdgcn_global_load_lds(
      (__attribute__((address_space(1))) void*)gsrc,
      (__attribute__((address_space(3))) void*)ldst,
      16, 0, 0);
}

__device__ __forceinline__ float fast_sigmoid(float x) {
  return 1.0f / (1.0f + __expf(-x));
}

__device__ __forceinline__ float fast_tanh(float x) {
  x = fminf(30.0f, fmaxf(-30.0f, x));
  float e = __expf(-2.0f * x);
  return (1.0f - e) / (1.0f + e);
}

// ---------- conversion kernels (tiled bf16 workspace) ----------

// hprev f32 [M][K] -> A_t[kt][M][64] bf16 (K-tile panels, 128 B rows)
__global__ void convert_h_tiled(const float* __restrict__ in,
                                unsigned short* __restrict__ out, int nchunk) {
  int idx = blockIdx.x * blockDim.x + threadIdx.x;
  int stride = gridDim.x * blockDim.x;
  for (int i = idx; i < nchunk; i += stride) {
    int r = i >> 7;
    int kc8 = i & 127;
    const float4* src = reinterpret_cast<const float4*>(in + (size_t)r * KDIM + kc8 * 8);
    float4 v0 = src[0], v1 = src[1];
    short8 o;
    o[0] = (short)f2bf(v0.x); o[1] = (short)f2bf(v0.y);
    o[2] = (short)f2bf(v0.z); o[3] = (short)f2bf(v0.w);
    o[4] = (short)f2bf(v1.x); o[5] = (short)f2bf(v1.y);
    o[6] = (short)f2bf(v1.z); o[7] = (short)f2bf(v1.w);
    int kt = kc8 >> 3;
    int c8 = kc8 & 7;
    reinterpret_cast<short8*>(out)[((size_t)kt * MDIM + r) * 8 + c8] = o;
  }
}

// w[k][n] f32 -> B_t[kt][g][N][64] bf16 (transpose + tile, 128 B rows)
__global__ void convert_w_tiled(const float* __restrict__ w0,
                                const float* __restrict__ w1,
                                const float* __restrict__ w2,
                                const float* __restrict__ w3,
                                unsigned short* __restrict__ out) {
  __shared__ float tile[64][65];
  int g = blockIdx.z;
  const float* w = (g == 0) ? w0 : (g == 1) ? w1 : (g == 2) ? w2 : w3;
  int kt = blockIdx.y;
  int k0 = kt * 64;
  int n0 = blockIdx.x * 64;
  int tx = threadIdx.x;
  int ty = threadIdx.y;
#pragma unroll
  for (int j = 0; j < 16; ++j) {
    int kk = ty * 16 + j;
    tile[kk][tx] = w[(size_t)(k0 + kk) * NDIM + n0 + tx];
  }
  __syncthreads();
#pragma unroll
  for (int j = 0; j < 16; ++j) {
    int nn = ty * 16 + j;
    out[(((size_t)kt * 4 + g) * NDIM + n0 + nn) * 64 + tx] = f2bf(tile[tx][nn]);
  }
}

// ---------- fused 4-gate GEMM: R1 structure + 32x32x16 MFMA ----------
//
// 1024 blocks (XCD-swizzled), 256 thr = 4 waves (2M x 2N).
// Block tile: 128 rows x (4 gates x 64 cols), BK=64; per wave 64x32/gate.
// MFMA 32x32x16 (2382 TF ubench vs 2075 for 16x16x32): per K-tile per
// wave 32 MFMA + 24 ds_read_b128 (same reads as 16x16 variant, half the
// MFMA instructions, +15% pipe rate).
// LDS 48 KB single-buffer { A[128][128B] | B[4][64][128B] }, XOR chunk
// swizzle slot=c^(row&7), pre-swizzled global source (contiguous 4 KB per
// glds instr from tiled workspace). m97-style 2-barrier loop (best of 8
// structural variants tested on this problem).

__global__ __launch_bounds__(256, 2) void lstm_fused_gemm(
    const unsigned short* __restrict__ At,    // [16][8192][64] bf16
    const unsigned short* __restrict__ Bt,    // [16][4][1024][64] bf16
    const float* __restrict__ cprev,
    const float* __restrict__ b_i, const float* __restrict__ b_f,
    const float* __restrict__ b_g, const float* __restrict__ b_o,
    float* __restrict__ out)
{
  __shared__ unsigned char ldsb[49152];
  const int tid  = threadIdx.x;
  const int lane = tid & 63;
  const int wave = tid >> 6;
  const int wr = wave >> 1;   // 0..1 : rows wr*64..+64
  const int wc = wave & 1;    // 0..1 : cols wc*32..+32 per gate
  const int l31 = lane & 31;
  const int hb5 = lane >> 5;  // k-half selector

  // XCD-bijective swizzle: 1024 blocks, 128/XCD.
  int bid = blockIdx.x;
  int swz = (bid & 7) * 128 + (bid >> 3);
  int mb = swz >> 4;        // 0..63
  int nb = swz & 15;        // 0..15
  int brow = mb * 128;
  int bcol = nb * 64;

  const char* ab = (const char*)At;
  const char* bb = (const char*)Bt;

  // staging source (pre-swizzled chunk within each 128 B line; contiguous
  // 4 KB per wave-instr thanks to the tiled workspace)
  const int srow = tid >> 3;                       // 0..31
  const int cx = (((tid & 7) ^ (srow & 7)) << 4);
  const uint32_t srcA = (uint32_t)(brow + srow) * 128 + cx;
  const uint32_t srcB = (uint32_t)(bcol + srow) * 128 + cx;

  // fragment read offsets: lane l reads row (l&31), 16 B at chunk
  // (ks*2 + (l>>5)) ^ (row&7)
  int sx[4];
#pragma unroll
  for (int ks = 0; ks < 4; ++ks)
    sx[ks] = (((ks * 2 + hb5) ^ (l31 & 7)) << 4);
  const uint32_t a_row = (uint32_t)(wr * 64 + l31) * 128;          // + mf*32*128
  const uint32_t b_row = 16384u + (uint32_t)(wc * 32 + l31) * 128; // + g*8192

  f32x16 acc[4][2];
#pragma unroll
  for (int g = 0; g < 4; ++g)
#pragma unroll
    for (int mf = 0; mf < 2; ++mf)
#pragma unroll
      for (int r = 0; r < 16; ++r)
        acc[g][mf][r] = 0.f;

  for (int t = 0; t < NKT; ++t) {
    // ---- stage tile t (single buffer): A 4 instr, B 8 instr ----
#pragma unroll
    for (int j = 0; j < 4; ++j)
      load_lds16(ab + ((uint32_t)t << 20) + srcA + j * 4096,
                 ldsb + j * 4096 + tid * 16);
#pragma unroll
    for (int g = 0; g < 4; ++g)
#pragma unroll
      for (int h = 0; h < 2; ++h)
        load_lds16(bb + ((uint32_t)t << 19) + (uint32_t)g * 131072 + srcB + h * 4096,
                   ldsb + 16384 + g * 8192 + h * 4096 + tid * 16);
    __syncthreads();   // compiler drains vmcnt before barrier

    // ---- compute: 4 ksteps x { 2 A-frags, 4 B-frags, 8 MFMA } ----
#pragma unroll
    for (int ks = 0; ks < 4; ++ks) {
      short8 A0 = *(const short8*)(ldsb + a_row + 0 * 4096 + sx[ks]);
      short8 A1 = *(const short8*)(ldsb + a_row + 1 * 4096 + sx[ks]);
#pragma unroll
      for (int g = 0; g < 4; ++g) {
        short8 Bg = *(const short8*)(ldsb + b_row + g * 8192 + sx[ks]);
        acc[g][0] = __builtin_amdgcn_mfma_f32_32x32x16_bf16(A0, Bg, acc[g][0], 0, 0, 0);
        acc[g][1] = __builtin_amdgcn_mfma_f32_32x32x16_bf16(A1, Bg, acc[g][1], 0, 0, 0);
      }
    }
    __syncthreads();   // protect LDS before next tile's stage
  }

  // ---- fused LSTM epilogue ----
  // 32x32 C/D layout (m74/m101): col = lane&31, row = (r&3)+8*(r>>2)+4*(lane>>5)
  const size_t outC = (size_t)MDIM * NDIM;
  const int cc = bcol + wc * 32 + l31;
  const float bi = b_i[cc], bff = b_f[cc], bg = b_g[cc], bo = b_o[cc];
#pragma unroll
  for (int mf = 0; mf < 2; ++mf) {
#pragma unroll
    for (int r = 0; r < 16; ++r) {
      int rr = brow + wr * 64 + mf * 32 + (r & 3) + 8 * (r >> 2) + 4 * hb5;
      size_t base = (size_t)rr * NDIM + cc;
      float pi = acc[0][mf][r] + bi;
      float pf = acc[1][mf][r] + bff;
      float pg = acc[2][mf][r] + bg;
      float po = acc[3][mf][r] + bo;
      float iv = fast_sigmoid(pi);
      float fv = fast_sigmoid(pf);
      float gv = fast_tanh(pg);
      float ov = fast_sigmoid(po);
      float cp = fv * cprev[base] + iv * gv;
      float hp = ov * fast_tanh(cp);
      out[base] = hp;
      out[outC + base] = cp;
    }
  }
}

// ---------- launch ----------

extern "C" void kernel_launch(void* const* d_in, const int* in_sizes, int n_in,
                              void* d_out, int out_size, void* d_ws, size_t ws_size,
                              hipStream_t stream) {
  const float* hprev = (const float*)d_in[0];
  const float* cprev = (const float*)d_in[1];
  const float* w_hi  = (const float*)d_in[2];
  const float* b_hi  = (const float*)d_in[3];
  const float* w_hf  = (const float*)d_in[4];
  const float* b_hf  = (const float*)d_in[5];
  const float* w_hg  = (const float*)d_in[6];
  const float* b_hg  = (const float*)d_in[7];
  const float* w_ho  = (const float*)d_in[8];
  const float* b_ho  = (const float*)d_in[9];
  float* out = (float*)d_out;

  // ws: [0,16MB) A_t; [16MB,24MB) B_t
  unsigned short* At = (unsigned short*)d_ws;
  unsigned short* Bt = (unsigned short*)((char*)d_ws + (size_t)NKT * MDIM * 64 * 2);

  convert_h_tiled<<<2048, 256, 0, stream>>>(hprev, At, MDIM * KDIM / 8);
  convert_w_tiled<<<dim3(16, 16, 4), dim3(64, 4, 1), 0, stream>>>(
      w_hi, w_hf, w_hg, w_ho, Bt);
  lstm_fused_gemm<<<1024, 256, 0, stream>>>(At, Bt, cprev,
                                            b_hi, b_hf, b_hg, b_ho, out);
}